// Round 8
// baseline (212.889 us; speedup 1.0000x reference)
//
#include <hip/hip_runtime.h>
#include <hip/hip_bf16.h>

// FeatureProcessingBlock: per 64x64 window, Out = sum_t Cs_t^T ( Hs_t^T @ X_c @ Ws_t )
// R8 = R7 + persistent workgroups: 256 wgs (1/CU), tile fixed per wg, 4 windows
//     sequentially; tables init once; cross-window prefetch keeps pipe full.
//     4 tile-wgs of a window run concurrently on one XCD (L2 time-sharing).

typedef __attribute__((ext_vector_type(8))) short short8;
typedef __attribute__((ext_vector_type(4))) short short4v;
typedef __attribute__((ext_vector_type(4))) float float4v;

#define SMEM_BYTES 145408
// Y1F @0:      [3t*8c][2 sv][64 lane][16B] = 49152
// Zb  @49152:  [4 kq][1024 px][16B] = 65536  (k=c*4+t; kq=c>>1; byte (c&1)*8+2t)
// Hf  @114688: [4 mt][3 t][2 sv][64 lane][16B] = 24576
// Wf  @139264: [3 t][2 sv][64 lane][16B] = 6144

static __device__ __forceinline__ unsigned short f2bf(float f) {
  return __builtin_bit_cast(unsigned short, __float2bfloat16(f));
}

__global__ __launch_bounds__(1024)
void fpb8(const float* __restrict__ x, const float* __restrict__ Ws,
          const float* __restrict__ Hsm, const float* __restrict__ Cs,
          float* __restrict__ out) {
  extern __shared__ char smem[];
  char* Y1F = smem;
  char* Zb  = smem + 49152;
  char* Hf  = smem + 114688;
  char* Wf  = smem + 139264;

  int xcd = blockIdx.x & 7, cu = blockIdx.x >> 3;
  int tile = cu & 3, wslot = cu >> 2;
  int j0 = tile * 16;

  int tid = threadIdx.x, lane = tid & 63, wave = tid >> 6;  // wave 0..15
  int lq = lane >> 4, lc = lane & 15;

  int cA  = wave & 7, hh = wave >> 3;   // A-phase roles
  int mtB = wave & 3, cq = wave >> 2;   // B-phase roles

  // ---- init once: Wf (A-phase B-operand frags of Ws) ----
  if (wave < 6) {
    int t = wave >> 1, sv = wave & 1;
    short8 v;
    #pragma unroll
    for (int e = 0; e < 8; ++e)
      v[e] = (short)f2bf(Ws[t * 4096 + (32 * sv + 8 * lq + e) * 64 + j0 + lc]);
    *(short8*)(Wf + wave * 1024 + lane * 16) = v;
  }
  // ---- init once: Hf (B-phase A-operand frags of Hs^T) ----
  for (int j = wave; j < 24; j += 16) {
    int mt = j / 6, r6 = j - 6 * mt, t = r6 >> 1, sv = r6 & 1;
    short8 v;
    #pragma unroll
    for (int e = 0; e < 8; ++e)
      v[e] = (short)f2bf(Hsm[t * 4096 + (32 * sv + 8 * lq + e) * 64 + 16 * mt + lc]);
    *(short8*)(Hf + j * 1024 + lane * 16) = v;
  }

  float4v acc[3][4];
  float4v fin[8];

  // ---- first prefetch: window w0, chunk 0 ----
  {
    int w0 = xcd * 32 + wslot;
    int b = w0 >> 6, p = (w0 >> 3) & 7, q = w0 & 7;
    const float* s0 = x + (((size_t)b * 48) * 512 + p * 64) * 512 + q * 64
                        + (size_t)cA * 262144 + (size_t)lc * 512 + 8 * lq;
    #pragma unroll
    for (int j2 = 0; j2 < 2; ++j2) {
      const float* r = s0 + (size_t)(2 * hh + j2) * 8192;
      fin[4*j2+0] = *(const float4v*)(r);
      fin[4*j2+1] = *(const float4v*)(r + 4);
      fin[4*j2+2] = *(const float4v*)(r + 32);
      fin[4*j2+3] = *(const float4v*)(r + 36);
    }
  }

  __syncthreads();   // Wf/Hf ready

  #pragma unroll 1
  for (int wit = 0; wit < 4; ++wit) {
    int window = xcd * 32 + wslot + 8 * wit;
    int b = window >> 6, p = (window >> 3) & 7, q = window & 7;
    const float* sA = x + (((size_t)b * 48) * 512 + p * 64) * 512 + q * 64
                        + (size_t)cA * 262144 + (size_t)lc * 512 + 8 * lq;
    int wn = (wit < 3) ? (window + 8) : window;
    int bn = wn >> 6, pn = (wn >> 3) & 7, qn = wn & 7;
    const float* sAn = x + (((size_t)bn * 48) * 512 + pn * 64) * 512 + qn * 64
                         + (size_t)cA * 262144 + (size_t)lc * 512 + 8 * lq;

    #pragma unroll
    for (int m = 0; m < 3; ++m)
      #pragma unroll
      for (int i = 0; i < 4; ++i) acc[m][i] = float4v{0.f, 0.f, 0.f, 0.f};

    for (int s = 0; s < 6; ++s) {
      // ======== A: Y1[t][cA] = X_c @ Ws_t (contract w); frag-major store ========
      {
        short8 af[4];
        #pragma unroll
        for (int j2 = 0; j2 < 2; ++j2) {
          short8 a0, a1;
          #pragma unroll
          for (int e2 = 0; e2 < 4; ++e2) {
            a0[e2]   = (short)f2bf(fin[4*j2+0][e2]);
            a0[4+e2] = (short)f2bf(fin[4*j2+1][e2]);
            a1[e2]   = (short)f2bf(fin[4*j2+2][e2]);
            a1[4+e2] = (short)f2bf(fin[4*j2+3][e2]);
          }
          af[2*j2] = a0; af[2*j2+1] = a1;
        }
        #pragma unroll
        for (int t = 0; t < 3; ++t) {
          short8 wf0 = *(const short8*)(Wf + (t * 2 + 0) * 1024 + lane * 16);
          short8 wf1 = *(const short8*)(Wf + (t * 2 + 1) * 1024 + lane * 16);
          #pragma unroll
          for (int j2 = 0; j2 < 2; ++j2) {
            float4v d = {0.f, 0.f, 0.f, 0.f};
            d = __builtin_amdgcn_mfma_f32_16x16x32_bf16(af[2*j2],   wf0, d, 0, 0, 0);
            d = __builtin_amdgcn_mfma_f32_16x16x32_bf16(af[2*j2+1], wf1, d, 0, 0, 0);
            int lqp = (2 * j2 + (lq >> 1)) & 3;
            short4v pv;
            pv[0] = (short)f2bf(d[0]); pv[1] = (short)f2bf(d[1]);
            pv[2] = (short)f2bf(d[2]); pv[3] = (short)f2bf(d[3]);
            *(short4v*)(Y1F + ((t * 8 + cA) * 2 + hh) * 1024
                            + (lqp * 16 + lc) * 16 + (lq & 1) * 8) = pv;
          }
        }
      }
      __syncthreads();   // Y1F complete

      // ======== B: Zb[kq][px] = Hs_t^T @ Y1 (contract h) ========
      {
        // Cs gather issued early (L2-hot; consumed at end of B)
        float craw[3][6];
        #pragma unroll
        for (int m = 0; m < 3; ++m)
          #pragma unroll
          for (int ch = 0; ch < 2; ++ch)
            #pragma unroll
            for (int t = 0; t < 3; ++t)
              craw[m][ch*3+t] =
                  Cs[t * 2304 + (8 * s + 2 * lq + ch) * 48 + 16 * m + lc];

        unsigned long long w64[2][4];
        #pragma unroll
        for (int t = 0; t < 3; ++t) {
          short8 hf0 = *(const short8*)(Hf + (mtB * 6 + t * 2 + 0) * 1024 + lane * 16);
          short8 hf1 = *(const short8*)(Hf + (mtB * 6 + t * 2 + 1) * 1024 + lane * 16);
          #pragma unroll
          for (int cj = 0; cj < 2; ++cj) {
            const char* yb = Y1F + ((t * 8 + 2 * cq + cj) * 2) * 1024 + lane * 16;
            short8 y0 = *(const short8*)yb;
            short8 y1 = *(const short8*)(yb + 1024);
            float4v dd = {0.f, 0.f, 0.f, 0.f};
            dd = __builtin_amdgcn_mfma_f32_16x16x32_bf16(hf0, y0, dd, 0, 0, 0);
            dd = __builtin_amdgcn_mfma_f32_16x16x32_bf16(hf1, y1, dd, 0, 0, 0);
            #pragma unroll
            for (int r = 0; r < 4; ++r) {
              unsigned long long v = (unsigned long long)f2bf(dd[r]) << (16 * t);
              if (t == 0) w64[cj][r] = v; else w64[cj][r] |= v;
            }
          }
        }
        #pragma unroll
        for (int cj = 0; cj < 2; ++cj)
          #pragma unroll
          for (int r = 0; r < 4; ++r) {
            int px = (16 * mtB + 4 * lq + r) * 16 + lc;
            *(unsigned long long*)(Zb + cq * 16384 + px * 16 + cj * 8) = w64[cj][r];
          }

        short8 cf[3];
        #pragma unroll
        for (int m = 0; m < 3; ++m) {
          short8 v;
          v[0] = (short)f2bf(craw[m][0]); v[1] = (short)f2bf(craw[m][1]);
          v[2] = (short)f2bf(craw[m][2]); v[3] = 0;
          v[4] = (short)f2bf(craw[m][3]); v[5] = (short)f2bf(craw[m][4]);
          v[6] = (short)f2bf(craw[m][5]); v[7] = 0;
          cf[m] = v;
        }
        __syncthreads();   // Zb complete

        // ======== C: acc += Cf @ Zb; refill fin (next chunk / next window) ========
        {
          const float* pre = (s < 5) ? (sA + (size_t)(s + 1) * 2097152) : sAn;
          #pragma unroll
          for (int j2 = 0; j2 < 2; ++j2) {
            const float* r = pre + (size_t)(2 * hh + j2) * 8192;
            fin[4*j2+0] = *(const float4v*)(r);
            fin[4*j2+1] = *(const float4v*)(r + 4);
            fin[4*j2+2] = *(const float4v*)(r + 32);
            fin[4*j2+3] = *(const float4v*)(r + 36);
          }
        }
        #pragma unroll
        for (int i = 0; i < 4; ++i) {
          int px = (wave + 16 * i) * 16 + lc;
          short8 zf = *(const short8*)(Zb + lq * 16384 + px * 16);
          acc[0][i] = __builtin_amdgcn_mfma_f32_16x16x32_bf16(cf[0], zf, acc[0][i], 0, 0, 0);
          acc[1][i] = __builtin_amdgcn_mfma_f32_16x16x32_bf16(cf[1], zf, acc[1][i], 0, 0, 0);
          acc[2][i] = __builtin_amdgcn_mfma_f32_16x16x32_bf16(cf[2], zf, acc[2][i], 0, 0, 0);
        }
      }
      // 2 barriers/chunk: next A's Y1F writes happen after this wave passed bar2.
    }

    // ---- epilogue (per window): fully static stores ----
    #pragma unroll
    for (int m = 0; m < 3; ++m)
      #pragma unroll
      for (int i = 0; i < 4; ++i) {
        int n = wave + 16 * i;
        #pragma unroll
        for (int r = 0; r < 4; ++r)
          out[(((size_t)(b * 48 + 16 * m + 4 * lq + r)) * 512 + p * 64 + n) * 512
              + q * 64 + j0 + lc] = acc[m][i][r];
      }
  }
}

extern "C" void kernel_launch(void* const* d_in, const int* in_sizes, int n_in,
                              void* d_out, int out_size, void* d_ws, size_t ws_size,
                              hipStream_t stream) {
  (void)in_sizes; (void)n_in; (void)d_ws; (void)ws_size; (void)out_size;
  const float* x   = (const float*)d_in[0];
  const float* Ws  = (const float*)d_in[1];
  const float* Hsm = (const float*)d_in[2];
  const float* Cs  = (const float*)d_in[3];
  float* out = (float*)d_out;
  (void)hipFuncSetAttribute((const void*)fpb8,
                            hipFuncAttributeMaxDynamicSharedMemorySize, SMEM_BYTES);
  fpb8<<<dim3(256), dim3(1024), SMEM_BYTES, stream>>>(x, Ws, Hsm, Cs, out);
}

// Round 9
// 212.128 us; speedup vs baseline: 1.0036x; 1.0036x over previous
//
#include <hip/hip_runtime.h>
#include <hip/hip_bf16.h>

// FeatureProcessingBlock: per 64x64 window, Out = sum_t Cs_t^T ( Hs_t^T @ X_c @ Ws_t )
// R9 = R4 (best, 162us) + ONLY the bank-conflict fix:
//   Zb -> [4 t-lines][1024 px][16B] (line 3 = persistent zeros): B-writes 2-way,
//   C-reads linear b128 conflict-free (both were 16-way in R4's 48B rows);
//   Cf slot-XOR lq^((lc>>2)&3) -> 2-way. Everything else byte-identical to R4.

typedef __attribute__((ext_vector_type(8))) short short8;
typedef __attribute__((ext_vector_type(4))) short short4v;
typedef __attribute__((ext_vector_type(4))) float float4v;

#define SMEM_BYTES 139264
// Y1 @0: [3t*8c][16lc x 72h] bf16 = 55296
// Zb @55296: [4 t][1024 px][16B] = 65536   (slot k=t*8+c at byte 2c; line 3 zeros)
// Cf @120832: [18 ss*m][16 lc][4 slot][16B] = 18432  (slot = lq ^ ((lc>>2)&3))

static __device__ __forceinline__ unsigned short f2bf(float f) {
  return __builtin_bit_cast(unsigned short, __float2bfloat16(f));
}
static __device__ __forceinline__ unsigned long long pk4(float a, float b, float c, float d) {
  unsigned long long lo = (unsigned int)((unsigned int)f2bf(a) | ((unsigned int)f2bf(b) << 16));
  unsigned long long hi = (unsigned int)((unsigned int)f2bf(c) | ((unsigned int)f2bf(d) << 16));
  return lo | (hi << 32);
}

__global__ __launch_bounds__(512, 2)
void fpb9(const float* __restrict__ x, const float* __restrict__ Ws,
          const float* __restrict__ Hsm, const float* __restrict__ Cs,
          float* __restrict__ out) {
  extern __shared__ char smem[];
  unsigned short* Y1 = (unsigned short*)smem;
  char* Zb = smem + 55296;
  char* Cf = smem + 120832;

  int wid = (blockIdx.x & 7) * 128 + (blockIdx.x >> 3);  // XCD swizzle
  int window = wid >> 2, tile = wid & 3;
  int b = window >> 6, p = (window >> 3) & 7, q = window & 7;
  int j0 = tile * 16;

  int tid = threadIdx.x, lane = tid & 63, wave = tid >> 6;
  int lq = lane >> 4, lc = lane & 15;
  int mt = wave & 3, cp = wave >> 2;
  int cslot = lq ^ ((lc >> 2) & 3);      // Cf bank-spread slot (involution)

  // ---- init: Zb zero line (read by C at lq==3; never overwritten) ----
  {
    char* zl = Zb + 3 * 16384 + tid * 32;
    *(unsigned long long*)(zl)      = 0ull;
    *(unsigned long long*)(zl + 8)  = 0ull;
    *(unsigned long long*)(zl + 16) = 0ull;
    *(unsigned long long*)(zl + 24) = 0ull;
  }
  // ---- init: Cf (k=t*8+c; lane lq holds t=lq, e=c; zeros baked at lq==3) ----
  for (int idx = wave; idx < 18; idx += 8) {
    int ss = idx / 3, m = idx - 3 * ss;
    short8 v;
    #pragma unroll
    for (int e = 0; e < 8; ++e)
      v[e] = (lq < 3) ? (short)f2bf(Cs[lq * 2304 + (8 * ss + e) * 48 + 16 * m + lc])
                      : (short)0;
    *(short8*)(Cf + ((idx * 16 + lc) * 4 + cslot) * 16) = v;
  }

  // persistent factor fragments
  short8 wsf[3][2], hsf[3][2];
  #pragma unroll
  for (int t = 0; t < 3; ++t)
    #pragma unroll
    for (int sv = 0; sv < 2; ++sv) {
      short8 aa, bb;
      #pragma unroll
      for (int e = 0; e < 8; ++e) {
        int k = 32 * sv + 8 * lq + e;
        aa[e] = (short)f2bf(Ws [t * 4096 + k * 64 + j0 + lc]);      // B: Ws[w][W']
        bb[e] = (short)f2bf(Hsm[t * 4096 + k * 64 + 16 * mt + lc]); // A: Hs^T[H'][h]
      }
      wsf[t][sv] = aa; hsf[t][sv] = bb;
    }

  float4v acc[3][8];
  #pragma unroll
  for (int m = 0; m < 3; ++m)
    #pragma unroll
    for (int i = 0; i < 8; ++i) acc[m][i] = float4v{0.f, 0.f, 0.f, 0.f};

  // A-stage: wave = c (within chunk); rows 16*mA+lc, cols 8*lq(+32)
  const float* xbase = x + (((size_t)b * 48) * 512 + p * 64) * 512 + q * 64
                         + (size_t)wave * 262144 + (size_t)lc * 512 + 8 * lq;

  float4v fin[2][8];   // two half-chunk prefetch slots
  #pragma unroll
  for (int h = 0; h < 2; ++h) {
    const float* src = xbase + (size_t)(32 * h) * 512;
    #pragma unroll
    for (int j2 = 0; j2 < 2; ++j2) {
      const float* r = src + (size_t)(16 * j2) * 512;
      fin[h][4*j2+0] = *(const float4v*)(r);
      fin[h][4*j2+1] = *(const float4v*)(r + 4);
      fin[h][4*j2+2] = *(const float4v*)(r + 32);
      fin[h][4*j2+3] = *(const float4v*)(r + 36);
    }
  }

  for (int s = 0; s < 6; ++s) {
    // ---- A: Y1[t][c=wave] = X_c @ Ws_t (contract w) ----
    #pragma unroll
    for (int h = 0; h < 2; ++h) {
      short8 af[4];
      #pragma unroll
      for (int j2 = 0; j2 < 2; ++j2) {
        short8 a0, a1;
        #pragma unroll
        for (int e2 = 0; e2 < 4; ++e2) {
          a0[e2]   = (short)f2bf(fin[h][4*j2+0][e2]);
          a0[4+e2] = (short)f2bf(fin[h][4*j2+1][e2]);
          a1[e2]   = (short)f2bf(fin[h][4*j2+2][e2]);
          a1[4+e2] = (short)f2bf(fin[h][4*j2+3][e2]);
        }
        af[2*j2] = a0; af[2*j2+1] = a1;
      }
      if (s < 5) {  // refill this slot for chunk s+1 (full-chunk latency cover)
        const float* src = xbase + (size_t)(s + 1) * 2097152 + (size_t)(32 * h) * 512;
        #pragma unroll
        for (int j2 = 0; j2 < 2; ++j2) {
          const float* r = src + (size_t)(16 * j2) * 512;
          fin[h][4*j2+0] = *(const float4v*)(r);
          fin[h][4*j2+1] = *(const float4v*)(r + 4);
          fin[h][4*j2+2] = *(const float4v*)(r + 32);
          fin[h][4*j2+3] = *(const float4v*)(r + 36);
        }
      }
      #pragma unroll
      for (int j2 = 0; j2 < 2; ++j2) {
        int mA = 2 * h + j2;
        #pragma unroll
        for (int t = 0; t < 3; ++t) {
          float4v d = {0.f, 0.f, 0.f, 0.f};
          d = __builtin_amdgcn_mfma_f32_16x16x32_bf16(af[2*j2],   wsf[t][0], d, 0, 0, 0);
          d = __builtin_amdgcn_mfma_f32_16x16x32_bf16(af[2*j2+1], wsf[t][1], d, 0, 0, 0);
          short4v pv;
          pv[0] = (short)f2bf(d[0]); pv[1] = (short)f2bf(d[1]);
          pv[2] = (short)f2bf(d[2]); pv[3] = (short)f2bf(d[3]);
          *(short4v*)&Y1[(t * 8 + wave) * 1152 + lc * 72 + 16 * mA + 4 * lq] = pv;
        }
      }
    }
    __syncthreads();

    // ---- B: Zb[t][px] = Hs_t^T @ Y1 (contract h); 2-way-free u64 writes ----
    #pragma unroll
    for (int t = 0; t < 3; ++t) {
      float4v dB[4];
      #pragma unroll
      for (int cj = 0; cj < 4; ++cj) {
        const unsigned short* ys = &Y1[(t * 8 + 4 * cp + cj) * 1152 + lc * 72 + 8 * lq];
        short8 y0 = *(const short8*)ys;
        short8 y1 = *(const short8*)(ys + 32);
        float4v dd = {0.f, 0.f, 0.f, 0.f};
        dd = __builtin_amdgcn_mfma_f32_16x16x32_bf16(hsf[t][0], y0, dd, 0, 0, 0);
        dd = __builtin_amdgcn_mfma_f32_16x16x32_bf16(hsf[t][1], y1, dd, 0, 0, 0);
        dB[cj] = dd;
      }
      #pragma unroll
      for (int r = 0; r < 4; ++r) {
        int px = (16 * mt + 4 * lq + r) * 16 + lc;
        *(unsigned long long*)(Zb + t * 16384 + px * 16 + 8 * cp) =
            pk4(dB[0][r], dB[1][r], dB[2][r], dB[3][r]);
      }
    }
    __syncthreads();

    // ---- C: acc += Cf @ Zb (contract t,c; K=32; line 3 = zeros, no branches) ----
    {
      short8 cf[3];
      #pragma unroll
      for (int m = 0; m < 3; ++m)
        cf[m] = *(const short8*)(Cf + (((s * 3 + m) * 16 + lc) * 4 + cslot) * 16);
      #pragma unroll
      for (int i = 0; i < 8; ++i) {
        int px = 16 * (wave + 8 * i) + lc;
        short8 zf = *(const short8*)(Zb + lq * 16384 + px * 16);
        acc[0][i] = __builtin_amdgcn_mfma_f32_16x16x32_bf16(cf[0], zf, acc[0][i], 0, 0, 0);
        acc[1][i] = __builtin_amdgcn_mfma_f32_16x16x32_bf16(cf[1], zf, acc[1][i], 0, 0, 0);
        acc[2][i] = __builtin_amdgcn_mfma_f32_16x16x32_bf16(cf[2], zf, acc[2][i], 0, 0, 0);
      }
    }
    // no barrier: C's Zb reads complete before next bar1 orders next B's writes;
    // next A touches Y1/global only (Y1 last read in B before bar2).
  }

  // ---- epilogue: fully static stores ----
  #pragma unroll
  for (int m = 0; m < 3; ++m)
    #pragma unroll
    for (int i = 0; i < 8; ++i) {
      int n = wave + 8 * i;
      size_t rowbase = (((size_t)(b * 48 + 16 * m + 4 * lq)) * 512 + p * 64 + n) * 512
                       + q * 64 + j0 + lc;
      #pragma unroll
      for (int r = 0; r < 4; ++r)
        out[rowbase + (size_t)r * 262144] = acc[m][i][r];
    }
}

extern "C" void kernel_launch(void* const* d_in, const int* in_sizes, int n_in,
                              void* d_out, int out_size, void* d_ws, size_t ws_size,
                              hipStream_t stream) {
  (void)in_sizes; (void)n_in; (void)d_ws; (void)ws_size; (void)out_size;
  const float* x   = (const float*)d_in[0];
  const float* Ws  = (const float*)d_in[1];
  const float* Hsm = (const float*)d_in[2];
  const float* Cs  = (const float*)d_in[3];
  float* out = (float*)d_out;
  (void)hipFuncSetAttribute((const void*)fpb9,
                            hipFuncAttributeMaxDynamicSharedMemorySize, SMEM_BYTES);
  fpb9<<<dim3(1024), dim3(512), SMEM_BYTES, stream>>>(x, Ws, Hsm, Cs, out);
}

// Round 10
// 186.191 us; speedup vs baseline: 1.1434x; 1.1393x over previous
//
#include <hip/hip_runtime.h>
#include <hip/hip_bf16.h>

// FeatureProcessingBlock: per 64x64 window, Out = sum_t Cs_t^T ( Hs_t^T @ X_c @ Ws_t )
// R10 = R4 (best known, 162us) + ONLY:
//   (1) 512 wgs x 2 windows each (same p,q, image b+2): pass-tails 4 -> 2,
//       cross-window prefetch through R4's existing refill slot (branch-free);
//   (2) s_setprio(1) around B- and C-phase MFMA clusters.
// Y1/Zb/Cf layouts, 2 barriers/chunk, prefetch, epilogue: byte-identical to R4.

typedef __attribute__((ext_vector_type(8))) short short8;
typedef __attribute__((ext_vector_type(4))) short short4v;
typedef __attribute__((ext_vector_type(4))) float float4v;

#define SMEM_BYTES 118288
// Y1 @0: [3t*8c][16lc x 72h] bf16 = 55296 | Zb @55296: [1024 px][48 B] = 49152
// Cf @104448: [18 ss*m][16 lc][48 B] = 13824 | z16 @118272: 16 B zeros

static __device__ __forceinline__ unsigned short f2bf(float f) {
  return __builtin_bit_cast(unsigned short, __float2bfloat16(f));
}
static __device__ __forceinline__ unsigned long long pk4(float a, float b, float c, float d) {
  unsigned long long lo = (unsigned int)((unsigned int)f2bf(a) | ((unsigned int)f2bf(b) << 16));
  unsigned long long hi = (unsigned int)((unsigned int)f2bf(c) | ((unsigned int)f2bf(d) << 16));
  return lo | (hi << 32);
}

__global__ __launch_bounds__(512, 2)
void fpb10(const float* __restrict__ x, const float* __restrict__ Ws,
           const float* __restrict__ Hsm, const float* __restrict__ Cs,
           float* __restrict__ out) {
  extern __shared__ char smem[];
  unsigned short* Y1 = (unsigned short*)smem;
  char* Zb  = smem + 55296;
  char* Cf  = smem + 104448;
  char* z16 = smem + 118272;

  int wid = (blockIdx.x & 7) * 64 + (blockIdx.x >> 3);   // XCD swizzle, 512 wgs
  int window0 = wid >> 2, tile = wid & 3;                // window0 in [0,128)
  int j0 = tile * 16;

  int tid = threadIdx.x, lane = tid & 63, wave = tid >> 6;
  int lq = lane >> 4, lc = lane & 15;
  int mt = wave & 3, cp = wave >> 2;

  if (tid < 4) ((unsigned int*)z16)[tid] = 0;

  // Cf init: row (ss*3+m, lc), slot k = t*8+cl -> lane lq holds t=lq, e=cl
  for (int idx = wave; idx < 18; idx += 8) {
    int ss = idx / 3, m = idx - 3 * ss;
    if (lq < 3) {
      short8 v;
      #pragma unroll
      for (int e = 0; e < 8; ++e)
        v[e] = (short)f2bf(Cs[lq * 2304 + (8 * ss + e) * 48 + 16 * m + lc]);
      *(short8*)(Cf + (idx * 16 + lc) * 48 + lq * 16) = v;
    }
  }

  // persistent factor fragments
  short8 wsf[3][2], hsf[3][2];
  #pragma unroll
  for (int t = 0; t < 3; ++t)
    #pragma unroll
    for (int sv = 0; sv < 2; ++sv) {
      short8 aa, bb;
      #pragma unroll
      for (int e = 0; e < 8; ++e) {
        int k = 32 * sv + 8 * lq + e;
        aa[e] = (short)f2bf(Ws [t * 4096 + k * 64 + j0 + lc]);      // B: Ws[w][W']
        bb[e] = (short)f2bf(Hsm[t * 4096 + k * 64 + 16 * mt + lc]); // A: Hs^T[H'][h]
      }
      wsf[t][sv] = aa; hsf[t][sv] = bb;
    }

  float4v fin[2][8];   // two half-chunk prefetch slots
  // ---- prologue prefetch: window0, chunk 0 ----
  {
    int b = window0 >> 6, p = (window0 >> 3) & 7, q = window0 & 7;
    const float* xb0 = x + (((size_t)b * 48) * 512 + p * 64) * 512 + q * 64
                         + (size_t)wave * 262144 + (size_t)lc * 512 + 8 * lq;
    #pragma unroll
    for (int h = 0; h < 2; ++h) {
      const float* src = xb0 + (size_t)(32 * h) * 512;
      #pragma unroll
      for (int j2 = 0; j2 < 2; ++j2) {
        const float* r = src + (size_t)(16 * j2) * 512;
        fin[h][4*j2+0] = *(const float4v*)(r);
        fin[h][4*j2+1] = *(const float4v*)(r + 4);
        fin[h][4*j2+2] = *(const float4v*)(r + 32);
        fin[h][4*j2+3] = *(const float4v*)(r + 36);
      }
    }
  }

  #pragma unroll 1
  for (int wit = 0; wit < 2; ++wit) {
    int window = window0 + 128 * wit;            // same p,q; image b+2 for wit=1
    int b = window >> 6, p = (window >> 3) & 7, q = window & 7;
    const float* xbase = x + (((size_t)b * 48) * 512 + p * 64) * 512 + q * 64
                           + (size_t)wave * 262144 + (size_t)lc * 512 + 8 * lq;
    // next-window base for the s==5 refill (wit==1: points at self, harmless reload)
    const float* xbn = (wit == 0) ? (xbase + (size_t)25165824) : xbase;

    float4v acc[3][8];
    #pragma unroll
    for (int m = 0; m < 3; ++m)
      #pragma unroll
      for (int i = 0; i < 8; ++i) acc[m][i] = float4v{0.f, 0.f, 0.f, 0.f};

    for (int s = 0; s < 6; ++s) {
      // ---- A: Y1[t][c=wave] = X_c @ Ws_t (contract w) ----
      #pragma unroll
      for (int h = 0; h < 2; ++h) {
        short8 af[4];
        #pragma unroll
        for (int j2 = 0; j2 < 2; ++j2) {
          short8 a0, a1;
          #pragma unroll
          for (int e2 = 0; e2 < 4; ++e2) {
            a0[e2]   = (short)f2bf(fin[h][4*j2+0][e2]);
            a0[4+e2] = (short)f2bf(fin[h][4*j2+1][e2]);
            a1[e2]   = (short)f2bf(fin[h][4*j2+2][e2]);
            a1[4+e2] = (short)f2bf(fin[h][4*j2+3][e2]);
          }
          af[2*j2] = a0; af[2*j2+1] = a1;
        }
        {  // refill this slot: next chunk, or next window's chunk 0
          const float* srcb = (s < 5) ? (xbase + (size_t)(s + 1) * 2097152) : xbn;
          const float* src  = srcb + (size_t)(32 * h) * 512;
          #pragma unroll
          for (int j2 = 0; j2 < 2; ++j2) {
            const float* r = src + (size_t)(16 * j2) * 512;
            fin[h][4*j2+0] = *(const float4v*)(r);
            fin[h][4*j2+1] = *(const float4v*)(r + 4);
            fin[h][4*j2+2] = *(const float4v*)(r + 32);
            fin[h][4*j2+3] = *(const float4v*)(r + 36);
          }
        }
        #pragma unroll
        for (int j2 = 0; j2 < 2; ++j2) {
          int mA = 2 * h + j2;
          #pragma unroll
          for (int t = 0; t < 3; ++t) {
            float4v d = {0.f, 0.f, 0.f, 0.f};
            d = __builtin_amdgcn_mfma_f32_16x16x32_bf16(af[2*j2],   wsf[t][0], d, 0, 0, 0);
            d = __builtin_amdgcn_mfma_f32_16x16x32_bf16(af[2*j2+1], wsf[t][1], d, 0, 0, 0);
            short4v pv;
            pv[0] = (short)f2bf(d[0]); pv[1] = (short)f2bf(d[1]);
            pv[2] = (short)f2bf(d[2]); pv[3] = (short)f2bf(d[3]);
            *(short4v*)&Y1[(t * 8 + wave) * 1152 + lc * 72 + 16 * mA + 4 * lq] = pv;
          }
        }
      }
      __syncthreads();

      // ---- B: Zb[px][k=t*8+cl] = Hs_t^T @ Y1 (contract h) ----
      __builtin_amdgcn_s_setprio(1);
      #pragma unroll
      for (int t = 0; t < 3; ++t) {
        float4v dB[4];
        #pragma unroll
        for (int cj = 0; cj < 4; ++cj) {
          const unsigned short* ys = &Y1[(t * 8 + 4 * cp + cj) * 1152 + lc * 72 + 8 * lq];
          short8 y0 = *(const short8*)ys;
          short8 y1 = *(const short8*)(ys + 32);
          float4v dd = {0.f, 0.f, 0.f, 0.f};
          dd = __builtin_amdgcn_mfma_f32_16x16x32_bf16(hsf[t][0], y0, dd, 0, 0, 0);
          dd = __builtin_amdgcn_mfma_f32_16x16x32_bf16(hsf[t][1], y1, dd, 0, 0, 0);
          dB[cj] = dd;
        }
        #pragma unroll
        for (int r = 0; r < 4; ++r) {
          int px = (16 * mt + 4 * lq + r) * 16 + lc;
          *(unsigned long long*)(Zb + px * 48 + 16 * t + 8 * cp) =
              pk4(dB[0][r], dB[1][r], dB[2][r], dB[3][r]);
        }
      }
      __builtin_amdgcn_s_setprio(0);
      __syncthreads();

      // ---- C: acc += Cf @ Zb (contract t,c; K=32, slots 24..31 zero) ----
      {
        short8 cf[3];
        #pragma unroll
        for (int m = 0; m < 3; ++m) {
          const char* csrc = (lq < 3) ? (Cf + ((s * 3 + m) * 16 + lc) * 48 + lq * 16) : z16;
          cf[m] = *(const short8*)csrc;
        }
        __builtin_amdgcn_s_setprio(1);
        #pragma unroll
        for (int i = 0; i < 8; ++i) {
          int px = 16 * (wave + 8 * i) + lc;
          const char* zsrc = (lq < 3) ? (Zb + px * 48 + 16 * lq) : z16;
          short8 zf = *(const short8*)zsrc;
          acc[0][i] = __builtin_amdgcn_mfma_f32_16x16x32_bf16(cf[0], zf, acc[0][i], 0, 0, 0);
          acc[1][i] = __builtin_amdgcn_mfma_f32_16x16x32_bf16(cf[1], zf, acc[1][i], 0, 0, 0);
          acc[2][i] = __builtin_amdgcn_mfma_f32_16x16x32_bf16(cf[2], zf, acc[2][i], 0, 0, 0);
        }
        __builtin_amdgcn_s_setprio(0);
      }
      // no barrier: C's Zb reads complete before next bar1 orders next B's writes;
      // next A touches Y1/global only (Y1 last read in B before bar2).
    }

    // ---- epilogue (per window): fully static stores ----
    #pragma unroll
    for (int m = 0; m < 3; ++m)
      #pragma unroll
      for (int i = 0; i < 8; ++i) {
        int n = wave + 8 * i;
        size_t rowbase = (((size_t)(b * 48 + 16 * m + 4 * lq)) * 512 + p * 64 + n) * 512
                         + q * 64 + j0 + lc;
        #pragma unroll
        for (int r = 0; r < 4; ++r)
          out[rowbase + (size_t)r * 262144] = acc[m][i][r];
      }
  }
}

extern "C" void kernel_launch(void* const* d_in, const int* in_sizes, int n_in,
                              void* d_out, int out_size, void* d_ws, size_t ws_size,
                              hipStream_t stream) {
  (void)in_sizes; (void)n_in; (void)d_ws; (void)ws_size; (void)out_size;
  const float* x   = (const float*)d_in[0];
  const float* Ws  = (const float*)d_in[1];
  const float* Hsm = (const float*)d_in[2];
  const float* Cs  = (const float*)d_in[3];
  float* out = (float*)d_out;
  (void)hipFuncSetAttribute((const void*)fpb10,
                            hipFuncAttributeMaxDynamicSharedMemorySize, SMEM_BYTES);
  fpb10<<<dim3(512), dim3(512), SMEM_BYTES, stream>>>(x, Ws, Hsm, Cs, out);
}

// Round 11
// 155.738 us; speedup vs baseline: 1.3670x; 1.1955x over previous
//
#include <hip/hip_runtime.h>
#include <hip/hip_bf16.h>

// FeatureProcessingBlock: per 64x64 window, Out = sum_t Cs_t^T ( Hs_t^T @ X_c @ Ws_t )
// R11 = R4 (best known, 162us) + exactly two fixes:
//   (1) Y1 -> fragment-major (R5-verified mapping): A-writes 2-way (free),
//       B-reads lane*16 linear (optimal). Y1 was the 8e6-conflict source.
//   (2) raw barriers {s_waitcnt lgkmcnt(0); s_barrier}: no vmcnt(0) drain,
//       A-phase global prefetch stays in flight across barriers (T4).
// Zb/Cf/roles/prefetch/epilogue byte-identical to R4.

typedef __attribute__((ext_vector_type(8))) short short8;
typedef __attribute__((ext_vector_type(4))) short short4v;
typedef __attribute__((ext_vector_type(4))) float float4v;

#define SMEM_BYTES 112144
// Y1F @0: [3t*8c][2 sv][64 lane][16B] = 49152  (B-operand fragment layout)
// Zb @49152: [1024 px][48 B] = 49152  (slot k=t*8+cl at byte 2k)
// Cf @98304: [18 ss*m][16 lc][48 B] = 13824 | z16 @112128: 16 B zeros

static __device__ __forceinline__ unsigned short f2bf(float f) {
  return __builtin_bit_cast(unsigned short, __float2bfloat16(f));
}
static __device__ __forceinline__ unsigned long long pk4(float a, float b, float c, float d) {
  unsigned long long lo = (unsigned int)((unsigned int)f2bf(a) | ((unsigned int)f2bf(b) << 16));
  unsigned long long hi = (unsigned int)((unsigned int)f2bf(c) | ((unsigned int)f2bf(d) << 16));
  return lo | (hi << 32);
}
// LDS-only barrier: orders ds ops, leaves global loads in flight (T4).
static __device__ __forceinline__ void wg_barrier_lds() {
  asm volatile("s_waitcnt lgkmcnt(0)" ::: "memory");
  __builtin_amdgcn_s_barrier();
  asm volatile("" ::: "memory");
}

__global__ __launch_bounds__(512, 2)
void fpb11(const float* __restrict__ x, const float* __restrict__ Ws,
           const float* __restrict__ Hsm, const float* __restrict__ Cs,
           float* __restrict__ out) {
  extern __shared__ char smem[];
  char* Y1F = smem;
  char* Zb  = smem + 49152;
  char* Cf  = smem + 98304;
  char* z16 = smem + 112128;

  int wid = (blockIdx.x & 7) * 128 + (blockIdx.x >> 3);  // XCD swizzle
  int window = wid >> 2, tile = wid & 3;
  int b = window >> 6, p = (window >> 3) & 7, q = window & 7;
  int j0 = tile * 16;

  int tid = threadIdx.x, lane = tid & 63, wave = tid >> 6;
  int lq = lane >> 4, lc = lane & 15;
  int mt = wave & 3, cp = wave >> 2;

  if (tid < 4) ((unsigned int*)z16)[tid] = 0;

  // Cf init: row (ss*3+m, lc), slot k = t*8+cl -> lane lq holds t=lq, e=cl
  for (int idx = wave; idx < 18; idx += 8) {
    int ss = idx / 3, m = idx - 3 * ss;
    if (lq < 3) {
      short8 v;
      #pragma unroll
      for (int e = 0; e < 8; ++e)
        v[e] = (short)f2bf(Cs[lq * 2304 + (8 * ss + e) * 48 + 16 * m + lc]);
      *(short8*)(Cf + (idx * 16 + lc) * 48 + lq * 16) = v;
    }
  }

  // persistent factor fragments
  short8 wsf[3][2], hsf[3][2];
  #pragma unroll
  for (int t = 0; t < 3; ++t)
    #pragma unroll
    for (int sv = 0; sv < 2; ++sv) {
      short8 aa, bb;
      #pragma unroll
      for (int e = 0; e < 8; ++e) {
        int k = 32 * sv + 8 * lq + e;
        aa[e] = (short)f2bf(Ws [t * 4096 + k * 64 + j0 + lc]);      // B: Ws[w][W']
        bb[e] = (short)f2bf(Hsm[t * 4096 + k * 64 + 16 * mt + lc]); // A: Hs^T[H'][h]
      }
      wsf[t][sv] = aa; hsf[t][sv] = bb;
    }

  float4v acc[3][8];
  #pragma unroll
  for (int m = 0; m < 3; ++m)
    #pragma unroll
    for (int i = 0; i < 8; ++i) acc[m][i] = float4v{0.f, 0.f, 0.f, 0.f};

  // A-stage: wave = c (within chunk); rows 16*mA+lc, cols 8*lq(+32)
  const float* xbase = x + (((size_t)b * 48) * 512 + p * 64) * 512 + q * 64
                         + (size_t)wave * 262144 + (size_t)lc * 512 + 8 * lq;

  float4v fin[2][8];   // two half-chunk prefetch slots
  #pragma unroll
  for (int h = 0; h < 2; ++h) {
    const float* src = xbase + (size_t)(32 * h) * 512;
    #pragma unroll
    for (int j2 = 0; j2 < 2; ++j2) {
      const float* r = src + (size_t)(16 * j2) * 512;
      fin[h][4*j2+0] = *(const float4v*)(r);
      fin[h][4*j2+1] = *(const float4v*)(r + 4);
      fin[h][4*j2+2] = *(const float4v*)(r + 32);
      fin[h][4*j2+3] = *(const float4v*)(r + 36);
    }
  }

  for (int s = 0; s < 6; ++s) {
    // ---- A: Y1F[t][c=wave] = X_c @ Ws_t (contract w); frag-major store ----
    #pragma unroll
    for (int h = 0; h < 2; ++h) {
      short8 af[4];
      #pragma unroll
      for (int j2 = 0; j2 < 2; ++j2) {
        short8 a0, a1;
        #pragma unroll
        for (int e2 = 0; e2 < 4; ++e2) {
          a0[e2]   = (short)f2bf(fin[h][4*j2+0][e2]);
          a0[4+e2] = (short)f2bf(fin[h][4*j2+1][e2]);
          a1[e2]   = (short)f2bf(fin[h][4*j2+2][e2]);
          a1[4+e2] = (short)f2bf(fin[h][4*j2+3][e2]);
        }
        af[2*j2] = a0; af[2*j2+1] = a1;
      }
      if (s < 5) {  // refill this slot for chunk s+1 (stays in flight across bars)
        const float* src = xbase + (size_t)(s + 1) * 2097152 + (size_t)(32 * h) * 512;
        #pragma unroll
        for (int j2 = 0; j2 < 2; ++j2) {
          const float* r = src + (size_t)(16 * j2) * 512;
          fin[h][4*j2+0] = *(const float4v*)(r);
          fin[h][4*j2+1] = *(const float4v*)(r + 4);
          fin[h][4*j2+2] = *(const float4v*)(r + 32);
          fin[h][4*j2+3] = *(const float4v*)(r + 36);
        }
      }
      #pragma unroll
      for (int j2 = 0; j2 < 2; ++j2) {
        int mA  = 2 * h + j2;
        int sv  = mA >> 1;
        int lqp = (2 * mA + (lq >> 1)) & 3;   // B-frag lane group (R5/R6-verified)
        int eo  = (lq & 1) * 8;
        #pragma unroll
        for (int t = 0; t < 3; ++t) {
          float4v d = {0.f, 0.f, 0.f, 0.f};
          d = __builtin_amdgcn_mfma_f32_16x16x32_bf16(af[2*j2],   wsf[t][0], d, 0, 0, 0);
          d = __builtin_amdgcn_mfma_f32_16x16x32_bf16(af[2*j2+1], wsf[t][1], d, 0, 0, 0);
          short4v pv;
          pv[0] = (short)f2bf(d[0]); pv[1] = (short)f2bf(d[1]);
          pv[2] = (short)f2bf(d[2]); pv[3] = (short)f2bf(d[3]);
          *(short4v*)(Y1F + ((t * 8 + wave) * 2 + sv) * 1024
                          + (lqp * 16 + lc) * 16 + eo) = pv;
        }
      }
    }
    wg_barrier_lds();

    // ---- B: Zb[px][k=t*8+cl] = Hs_t^T @ Y1F (contract h); linear frag reads ----
    #pragma unroll
    for (int t = 0; t < 3; ++t) {
      float4v dB[4];
      #pragma unroll
      for (int cj = 0; cj < 4; ++cj) {
        const char* yb = Y1F + ((t * 8 + 4 * cp + cj) * 2) * 1024 + lane * 16;
        short8 y0 = *(const short8*)yb;
        short8 y1 = *(const short8*)(yb + 1024);
        float4v dd = {0.f, 0.f, 0.f, 0.f};
        dd = __builtin_amdgcn_mfma_f32_16x16x32_bf16(hsf[t][0], y0, dd, 0, 0, 0);
        dd = __builtin_amdgcn_mfma_f32_16x16x32_bf16(hsf[t][1], y1, dd, 0, 0, 0);
        dB[cj] = dd;
      }
      #pragma unroll
      for (int r = 0; r < 4; ++r) {
        int px = (16 * mt + 4 * lq + r) * 16 + lc;
        *(unsigned long long*)(Zb + px * 48 + 16 * t + 8 * cp) =
            pk4(dB[0][r], dB[1][r], dB[2][r], dB[3][r]);
      }
    }
    wg_barrier_lds();

    // ---- C: acc += Cf @ Zb (contract t,c; K=32, slots 24..31 zero) ----
    {
      short8 cf[3];
      #pragma unroll
      for (int m = 0; m < 3; ++m) {
        const char* csrc = (lq < 3) ? (Cf + ((s * 3 + m) * 16 + lc) * 48 + lq * 16) : z16;
        cf[m] = *(const short8*)csrc;
      }
      #pragma unroll
      for (int i = 0; i < 8; ++i) {
        int px = 16 * (wave + 8 * i) + lc;
        const char* zsrc = (lq < 3) ? (Zb + px * 48 + 16 * lq) : z16;
        short8 zf = *(const short8*)zsrc;
        acc[0][i] = __builtin_amdgcn_mfma_f32_16x16x32_bf16(cf[0], zf, acc[0][i], 0, 0, 0);
        acc[1][i] = __builtin_amdgcn_mfma_f32_16x16x32_bf16(cf[1], zf, acc[1][i], 0, 0, 0);
        acc[2][i] = __builtin_amdgcn_mfma_f32_16x16x32_bf16(cf[2], zf, acc[2][i], 0, 0, 0);
      }
    }
    // no barrier: C's Zb reads complete before next bar1 orders next B's writes;
    // next A writes Y1F only (last read in B before bar2).
  }

  // ---- epilogue: fully static stores ----
  #pragma unroll
  for (int m = 0; m < 3; ++m)
    #pragma unroll
    for (int i = 0; i < 8; ++i) {
      int n = wave + 8 * i;
      size_t rowbase = (((size_t)(b * 48 + 16 * m + 4 * lq)) * 512 + p * 64 + n) * 512
                       + q * 64 + j0 + lc;
      #pragma unroll
      for (int r = 0; r < 4; ++r)
        out[rowbase + (size_t)r * 262144] = acc[m][i][r];
    }
}

extern "C" void kernel_launch(void* const* d_in, const int* in_sizes, int n_in,
                              void* d_out, int out_size, void* d_ws, size_t ws_size,
                              hipStream_t stream) {
  (void)in_sizes; (void)n_in; (void)d_ws; (void)ws_size; (void)out_size;
  const float* x   = (const float*)d_in[0];
  const float* Ws  = (const float*)d_in[1];
  const float* Hsm = (const float*)d_in[2];
  const float* Cs  = (const float*)d_in[3];
  float* out = (float*)d_out;
  (void)hipFuncSetAttribute((const void*)fpb11,
                            hipFuncAttributeMaxDynamicSharedMemorySize, SMEM_BYTES);
  fpb11<<<dim3(1024), dim3(512), SMEM_BYTES, stream>>>(x, Ws, Hsm, Cs, out);
}